// Round 11
// baseline (147885.474 us; speedup 1.0000x reference)
//
#include <hip/hip_runtime.h>
#include <cstdint>
#include <cmath>

// ---------------------------------------------------------------------------
// DDSP decoder on MI355X — inputs/outputs float32 (per reference dtypes).
//   1) precompute: gi_t = f0_t*U + loud_t*V + W  (input GEMM is rank-2+const)
//   2) persistent GRU: r11 = 64 blocks x 256 thr, 16 cols/block; Wh slice in
//      LDS as bf16 (100 KB, row-padded) unpacked on the fly. Fused
//      h-exchange+barrier (r8-r10): block publishes 16 f32 h values in its
//      own 128B slot = 6 tagged quads (tag==step validates each 16B quad; no
//      fences). Parity double-buffered slot sets (overwrite-safe by
//      induction). r10 post-mortem: sc0 vs sc1 identical -> coherence point
//      is the memory-side IC either way; ~12 poll sweeps/step => the cost is
//      contention (16K pollers) x straggler(max over 128). r11 halves both
//      (64 blocks) + role-split waves (wave0 poll, wave1 publish, wave2
//      hall) so the poller wave never drains foreign stores + s_sleep
//      throttle in the spin loop.
//   3) 3x (64x64-tile GEMM bf16-in/f32-acc/bf16-out + bias) + LN+ReLU.
//   4) heads: per-t block; amp/harm/noise projections, exp_sigmoid, normalize.
// ---------------------------------------------------------------------------

#define T_STEPS 32768
#define H_DIM   1024
#define H3      3072
#define NHARM   100
#define NNOISE  65
#define GRU_NB  64
#define GRU_CPB 16     // columns (h outputs) per block
#define WROW    1040   // padded LDS row stride (ushorts) to break bank aliasing

typedef unsigned short u16;
typedef unsigned uv4 __attribute__((ext_vector_type(4)));

__device__ __forceinline__ float b2f(u16 u) {
  union { unsigned u; float f; } x; x.u = ((unsigned)u) << 16; return x.f;
}
__device__ __forceinline__ u16 f2b(float f) {
  unsigned v = __float_as_uint(f);
  unsigned r = (v + 0x7FFFu + ((v >> 16) & 1u)) >> 16;  // RNE
  return (u16)r;
}
__device__ __forceinline__ float sigm(float x) { return 1.0f / (1.0f + expf(-x)); }
__device__ __forceinline__ float exp_sig(float x) {
  float s = sigm(x);
  return 2.0f * expf(2.302585093f * logf(s)) + 1e-7f;  // 2*sigm^ln10 + 1e-7
}

// 96B slot read: 6 dwordx4 back-to-back, one drain — one IC access latency
// for all tags AND data (sc1 = L2-bypass, coherent at the Infinity Cache).
__device__ __forceinline__ void bypass_load_6x4(const unsigned* p,
    uv4& a, uv4& b, uv4& c, uv4& d, uv4& e, uv4& f) {
  asm volatile("global_load_dwordx4 %0, %6, off sc1\n\t"
               "global_load_dwordx4 %1, %6, off offset:16 sc1\n\t"
               "global_load_dwordx4 %2, %6, off offset:32 sc1\n\t"
               "global_load_dwordx4 %3, %6, off offset:64 sc1\n\t"
               "global_load_dwordx4 %4, %6, off offset:80 sc1\n\t"
               "global_load_dwordx4 %5, %6, off offset:96 sc1\n\t"
               "s_waitcnt vmcnt(0)"
               : "=v"(a), "=v"(b), "=v"(c), "=v"(d), "=v"(e), "=v"(f)
               : "v"(p) : "memory");
}
__device__ __forceinline__ void bypass_store_x4(unsigned* p, uv4 v) {
  asm volatile("global_store_dwordx4 %0, %1, off sc1"
               :: "v"(p), "v"(v) : "memory");
}

// slots: 2 parity sets x 64 blocks x 32 u32 (128B slot = 2 lines).
// quads at u32 offsets {0,4,8,16,20,24}; quad q = [tag, v3q, v3q+1, v3q+2].

// ---------------------------------------------------------------------------
__global__ __launch_bounds__(256) void ddsp_precompute(
    const float* __restrict__ Win, const float* __restrict__ bin,
    const float* __restrict__ Wi, const float* __restrict__ h0,
    float* __restrict__ U, float* __restrict__ V, float* __restrict__ Wc,
    unsigned* __restrict__ slots)
{
  const int gid = blockIdx.x * 256 + threadIdx.x;
  if (blockIdx.x < 12) {
    const int j = gid;  // 0..3071
    float su = 0.f, sv = 0.f, sw = 0.f;
    for (int h = 0; h < H_DIM; ++h) {
      const float wv = Wi[h * H3 + j];
      su = fmaf(Win[h], wv, su);
      sv = fmaf(Win[H_DIM + h], wv, sv);
      sw = fmaf(bin[h], wv, sw);
    }
    U[j] = su; V[j] = sv; Wc[j] = sw;
  } else {
    const int idx = gid - 12 * 256;           // 0..1023
    if (idx < GRU_NB) {
      unsigned* l = slots + idx * 32;               // parity-0: tag0 + h0 data
      unsigned* m = slots + GRU_NB * 32 + idx * 32; // parity-1: tag0 (!=1)
      const int qo[6] = {0, 4, 8, 16, 20, 24};
#pragma unroll
      for (int q = 0; q < 6; ++q) {
        l[qo[q]] = 0u; m[qo[q]] = 0u;
#pragma unroll
        for (int j2 = 0; j2 < 3; ++j2) {
          const int v = q * 3 + j2;
          if (v < GRU_CPB) l[qo[q] + 1 + j2] = __float_as_uint(h0[idx * GRU_CPB + v]);
        }
      }
    }
  }
}

// ---------------------------------------------------------------------------
// persistent GRU. 64 blocks x 256 thr. thread = (jl = tid>>4 col 0..15,
// i = tid&15 k-chunk of 64). Wh slice [3][16][1024] bf16 in LDS (padded rows).
// Per step: wave0 polls 64 slots (1/lane; own block served from LDS) -> lds_h;
// all: 24 b128 bf16 weight reads + 16 h reads + 192 unpack + 192 FMA;
// 16-lane reduce; leaders (i==0) gates -> lds_hout; wave1 lane publishes the
// 6 tagged quads; wave2 lanes 128..143 write hall history.
// ---------------------------------------------------------------------------
__global__ __launch_bounds__(256, 1) void ddsp_gru(
    const float* __restrict__ f0, const float* __restrict__ loud,
    const float* __restrict__ Wh, const float* __restrict__ bh,
    const float* __restrict__ U, const float* __restrict__ V,
    const float* __restrict__ Wc, const float* __restrict__ h0,
    unsigned* __restrict__ slots, u16* __restrict__ hall)
{
  __shared__ u16 wlds[3 * GRU_CPB * WROW];   // ~100 KB bf16 weights
  __shared__ float lds_h[H_DIM];             // 4 KB
  __shared__ float lds_hout[GRU_CPB];
  const int tid = threadIdx.x;
  const int i  = tid & 15;
  const int jl = tid >> 4;
  const int jg = blockIdx.x * GRU_CPB + jl;

  // One-time bf16 weight stage: wlds[(g*16+c)*WROW + k] = bf16(Wh[k][col]).
  for (int g = 0; g < 3; ++g) {
    for (int c = 0; c < GRU_CPB; ++c) {
      const int col = g * H_DIM + blockIdx.x * GRU_CPB + c;
      const int row = (g * GRU_CPB + c) * WROW;
#pragma unroll
      for (int e = 0; e < 4; ++e) {
        const int k = tid * 4 + e;
        wlds[row + k] = f2b(Wh[(size_t)k * H3 + col]);
      }
    }
  }
  if (tid < GRU_CPB) lds_hout[tid] = h0[blockIdx.x * GRU_CPB + tid];

  float ur = 0.f, uz = 0.f, un = 0.f, vr = 0.f, vz = 0.f, vn = 0.f;
  float wr = 0.f, wz = 0.f, wn = 0.f, bhr = 0.f, bhz = 0.f, bhn = 0.f;
  if (i == 0) {
    ur = U[jg]; uz = U[jg + 1024]; un = U[jg + 2048];
    vr = V[jg]; vz = V[jg + 1024]; vn = V[jg + 2048];
    wr = Wc[jg]; wz = Wc[jg + 1024]; wn = Wc[jg + 2048];
    bhr = bh[jg]; bhz = bh[jg + 1024]; bhn = bh[jg + 2048];
  }
  __syncthreads();

  const int rb0 = (0 * GRU_CPB + jl) * WROW;
  const int rb1 = (1 * GRU_CPB + jl) * WROW;
  const int rb2 = (2 * GRU_CPB + jl) * WROW;

  for (int t = 0; t < T_STEPS; ++t) {
    const unsigned tag = (unsigned)t;
    unsigned* slot_rd = slots + (size_t)(t & 1) * GRU_NB * 32;
    unsigned* slot_wr = slots + (size_t)((t + 1) & 1) * GRU_NB * 32;

    const float fv = f0[t];
    const float lv = loud[t];

    // wave0: poll+assemble. lane ln owns slot ln; own block comes from LDS.
    if (tid < GRU_NB) {
      if (tid == blockIdx.x) {
        *(float4*)(lds_h + tid * 16)      = *(const float4*)(lds_hout);
        *(float4*)(lds_h + tid * 16 + 4)  = *(const float4*)(lds_hout + 4);
        *(float4*)(lds_h + tid * 16 + 8)  = *(const float4*)(lds_hout + 8);
        *(float4*)(lds_h + tid * 16 + 12) = *(const float4*)(lds_hout + 12);
      } else {
        const unsigned* base = slot_rd + tid * 32;
        uv4 a, b, c, d, e, f;
        int spin = 0;
        for (;;) {
          bypass_load_6x4(base, a, b, c, d, e, f);
          if (a.x == tag && b.x == tag && c.x == tag &&
              d.x == tag && e.x == tag && f.x == tag) break;
          if (++spin >= 2) __builtin_amdgcn_s_sleep(1);  // throttle IC traffic
        }
        float4 h0v, h1v, h2v, h3v;
        h0v.x = __uint_as_float(a.y); h0v.y = __uint_as_float(a.z);
        h0v.z = __uint_as_float(a.w); h0v.w = __uint_as_float(b.y);
        h1v.x = __uint_as_float(b.z); h1v.y = __uint_as_float(b.w);
        h1v.z = __uint_as_float(c.y); h1v.w = __uint_as_float(c.z);
        h2v.x = __uint_as_float(c.w); h2v.y = __uint_as_float(d.y);
        h2v.z = __uint_as_float(d.z); h2v.w = __uint_as_float(d.w);
        h3v.x = __uint_as_float(e.y); h3v.y = __uint_as_float(e.z);
        h3v.z = __uint_as_float(e.w); h3v.w = __uint_as_float(f.y);
        *(float4*)(lds_h + tid * 16)      = h0v;
        *(float4*)(lds_h + tid * 16 + 4)  = h1v;
        *(float4*)(lds_h + tid * 16 + 8)  = h2v;
        *(float4*)(lds_h + tid * 16 + 12) = h3v;
      }
    }
    __syncthreads();

    float a0 = 0.f, a1 = 0.f, a2 = 0.f;
    const int kbase = i << 6;  // i*64
#pragma unroll
    for (int it = 0; it < 8; ++it) {
      const int k = kbase + (((it + i) & 7) << 3);  // 8 k-values, rotated
      const float4 hA = *(const float4*)(lds_h + k);
      const float4 hB = *(const float4*)(lds_h + k + 4);
#define FMA8(RB, ACC)                                                     \
      {                                                                   \
        const uv4 wv = *(const uv4*)(wlds + RB + k);                      \
        ACC = fmaf(__uint_as_float(wv.x << 16), hA.x, ACC);               \
        ACC = fmaf(__uint_as_float(wv.x & 0xffff0000u), hA.y, ACC);       \
        ACC = fmaf(__uint_as_float(wv.y << 16), hA.z, ACC);               \
        ACC = fmaf(__uint_as_float(wv.y & 0xffff0000u), hA.w, ACC);       \
        ACC = fmaf(__uint_as_float(wv.z << 16), hB.x, ACC);               \
        ACC = fmaf(__uint_as_float(wv.z & 0xffff0000u), hB.y, ACC);       \
        ACC = fmaf(__uint_as_float(wv.w << 16), hB.z, ACC);               \
        ACC = fmaf(__uint_as_float(wv.w & 0xffff0000u), hB.w, ACC);       \
      }
      FMA8(rb0, a0)
      FMA8(rb1, a1)
      FMA8(rb2, a2)
#undef FMA8
    }
    // butterfly reduce over the 16-lane group
#pragma unroll
    for (int m = 1; m < 16; m <<= 1) {
      a0 += __shfl_xor(a0, m);
      a1 += __shfl_xor(a1, m);
      a2 += __shfl_xor(a2, m);
    }
    if (i == 0) {
      const float gir = fmaf(fv, ur, fmaf(lv, vr, wr));
      const float giz = fmaf(fv, uz, fmaf(lv, vz, wz));
      const float gin = fmaf(fv, un, fmaf(lv, vn, wn));
      const float r = sigm(gir + a0 + bhr);
      const float z = sigm(giz + a1 + bhz);
      const float n = tanhf(fmaf(r, a2 + bhn, gin));  // b_h[n] inside r*( )
      const float hp = lds_h[jg];
      lds_hout[jl] = (1.0f - z) * n + z * hp;
    }
    __syncthreads();

    // wave1 lane publishes (poller wave never drains these stores);
    // parity double-buffer + per-quad tags keep it fence-free.
    if (tid == 64) {
      const unsigned ntag = (unsigned)(t + 1);
      unsigned* base = slot_wr + blockIdx.x * 32;
      const float* ho = lds_hout;
      uv4 q;
      q.x = ntag;
      q.y = __float_as_uint(ho[0]); q.z = __float_as_uint(ho[1]); q.w = __float_as_uint(ho[2]);
      bypass_store_x4(base + 0, q);
      q.y = __float_as_uint(ho[3]); q.z = __float_as_uint(ho[4]); q.w = __float_as_uint(ho[5]);
      bypass_store_x4(base + 4, q);
      q.y = __float_as_uint(ho[6]); q.z = __float_as_uint(ho[7]); q.w = __float_as_uint(ho[8]);
      bypass_store_x4(base + 8, q);
      q.y = __float_as_uint(ho[9]); q.z = __float_as_uint(ho[10]); q.w = __float_as_uint(ho[11]);
      bypass_store_x4(base + 16, q);
      q.y = __float_as_uint(ho[12]); q.z = __float_as_uint(ho[13]); q.w = __float_as_uint(ho[14]);
      bypass_store_x4(base + 20, q);
      q.y = __float_as_uint(ho[15]); q.z = 0u; q.w = 0u;
      bypass_store_x4(base + 24, q);
    }
    // wave2 writes history (drains at its own barrier, off the poll path)
    if (tid >= 128 && tid < 128 + GRU_CPB) {
      const int c = tid - 128;
      hall[(size_t)t * H_DIM + blockIdx.x * GRU_CPB + c] = f2b(lds_hout[c]);
    }
  }
}

// ---------------------------------------------------------------------------
// GEMM: Y[T,1024](bf16) = X[T,1024](bf16) @ W[1024,1024](f32) + bias(f32)
// ---------------------------------------------------------------------------
__global__ __launch_bounds__(256) void ddsp_gemm_bias(
    const u16* __restrict__ X, const float* __restrict__ Wt,
    const float* __restrict__ bias, u16* __restrict__ Y)
{
  __shared__ float As[16][64];
  __shared__ float Bs[16][64];
  const int tid = threadIdx.x;
  const int R0 = blockIdx.x * 64;
  const int N0 = blockIdx.y * 64;
  const int tx = tid & 15, ty = tid >> 4;
  const int am = tid >> 2, ak = (tid & 3) * 4;
  const int bk = tid >> 4, bn = (tid & 15) * 4;
  float acc[4][4] = {};

  for (int k0 = 0; k0 < H_DIM; k0 += 16) {
    const ushort4 a4 = *(const ushort4*)(X + (size_t)(R0 + am) * H_DIM + k0 + ak);
    const float4 b4 = *(const float4*)(Wt + (size_t)(k0 + bk) * H_DIM + N0 + bn);
    As[ak + 0][am] = b2f(a4.x); As[ak + 1][am] = b2f(a4.y);
    As[ak + 2][am] = b2f(a4.z); As[ak + 3][am] = b2f(a4.w);
    *(float4*)&Bs[bk][bn] = b4;
    __syncthreads();
#pragma unroll
    for (int kk = 0; kk < 16; ++kk) {
      const float4 av = *(const float4*)&As[kk][ty * 4];
      const float4 bv = *(const float4*)&Bs[kk][tx * 4];
      const float a[4] = {av.x, av.y, av.z, av.w};
      const float b[4] = {bv.x, bv.y, bv.z, bv.w};
#pragma unroll
      for (int mi = 0; mi < 4; ++mi)
#pragma unroll
        for (int ni = 0; ni < 4; ++ni)
          acc[mi][ni] = fmaf(a[mi], b[ni], acc[mi][ni]);
    }
    __syncthreads();
  }
  const float4 bv4 = *(const float4*)(bias + N0 + tx * 4);
#pragma unroll
  for (int mi = 0; mi < 4; ++mi) {
    ushort4 st;
    st.x = f2b(acc[mi][0] + bv4.x);
    st.y = f2b(acc[mi][1] + bv4.y);
    st.z = f2b(acc[mi][2] + bv4.z);
    st.w = f2b(acc[mi][3] + bv4.w);
    *(ushort4*)(Y + (size_t)(R0 + ty * 4 + mi) * H_DIM + N0 + tx * 4) = st;
  }
}

// ---------------------------------------------------------------------------
__global__ __launch_bounds__(256) void ddsp_ln_relu(
    u16* __restrict__ Y, const float* __restrict__ scale, const float* __restrict__ bias)
{
  __shared__ float wsum[4], wsq[4];
  const int row = blockIdx.x, tid = threadIdx.x;
  const ushort4 r4 = *(const ushort4*)(Y + (size_t)row * H_DIM + tid * 4);
  float x[4] = {b2f(r4.x), b2f(r4.y), b2f(r4.z), b2f(r4.w)};
  float s = x[0] + x[1] + x[2] + x[3];
  float q = x[0] * x[0] + x[1] * x[1] + x[2] * x[2] + x[3] * x[3];
#pragma unroll
  for (int off = 32; off >= 1; off >>= 1) {
    s += __shfl_down(s, off);
    q += __shfl_down(q, off);
  }
  if ((tid & 63) == 0) { wsum[tid >> 6] = s; wsq[tid >> 6] = q; }
  __syncthreads();
  const float ts = wsum[0] + wsum[1] + wsum[2] + wsum[3];
  const float tq = wsq[0] + wsq[1] + wsq[2] + wsq[3];
  const float mu = ts * (1.0f / H_DIM);
  const float var = tq * (1.0f / H_DIM) - mu * mu;
  const float rstd = rsqrtf(fmaxf(var, 0.f) + 1e-6f);
  const float4 sc = *(const float4*)(scale + tid * 4);
  const float4 bi = *(const float4*)(bias + tid * 4);
  ushort4 st;
  st.x = f2b(fmaxf((x[0] - mu) * rstd * sc.x + bi.x, 0.f));
  st.y = f2b(fmaxf((x[1] - mu) * rstd * sc.y + bi.y, 0.f));
  st.z = f2b(fmaxf((x[2] - mu) * rstd * sc.z + bi.z, 0.f));
  st.w = f2b(fmaxf((x[3] - mu) * rstd * sc.w + bi.w, 0.f));
  *(ushort4*)(Y + (size_t)row * H_DIM + tid * 4) = st;
}

// ---------------------------------------------------------------------------
__global__ __launch_bounds__(256) void ddsp_heads(
    const u16* __restrict__ Hf,
    const float* __restrict__ aW, const float* __restrict__ ab,
    const float* __restrict__ hW, const float* __restrict__ hb,
    const float* __restrict__ nW, const float* __restrict__ nb,
    float* __restrict__ out)
{
  __shared__ float lh[H_DIM];
  __shared__ float se[128];
  __shared__ float sred[2];
  const int t = blockIdx.x, tid = threadIdx.x;
  const ushort4 h4 = *(const ushort4*)(Hf + (size_t)t * H_DIM + tid * 4);
  lh[tid * 4 + 0] = b2f(h4.x); lh[tid * 4 + 1] = b2f(h4.y);
  lh[tid * 4 + 2] = b2f(h4.z); lh[tid * 4 + 3] = b2f(h4.w);
  __syncthreads();

  if (tid < NHARM) {
    float acc = 0.f;
    for (int k = 0; k < H_DIM; k += 4) {
      const float4 hv = *(const float4*)(lh + k);
      acc = fmaf(hv.x, hW[(k + 0) * NHARM + tid], acc);
      acc = fmaf(hv.y, hW[(k + 1) * NHARM + tid], acc);
      acc = fmaf(hv.z, hW[(k + 2) * NHARM + tid], acc);
      acc = fmaf(hv.w, hW[(k + 3) * NHARM + tid], acc);
    }
    se[tid] = exp_sig(acc + hb[tid]);
  } else if (tid < NHARM + NNOISE) {
    const int n = tid - NHARM;
    float acc = 0.f;
    for (int k = 0; k < H_DIM; k += 4) {
      const float4 hv = *(const float4*)(lh + k);
      acc = fmaf(hv.x, nW[(k + 0) * NNOISE + n], acc);
      acc = fmaf(hv.y, nW[(k + 1) * NNOISE + n], acc);
      acc = fmaf(hv.z, nW[(k + 2) * NNOISE + n], acc);
      acc = fmaf(hv.w, nW[(k + 3) * NNOISE + n], acc);
    }
    out[(size_t)T_STEPS * NHARM + (size_t)t * NNOISE + n] = acc + nb[n];
  } else if (tid == NHARM + NNOISE) {
    float acc = 0.f;
    for (int k = 0; k < H_DIM; k += 4) {
      const float4 hv = *(const float4*)(lh + k);
      acc = fmaf(hv.x, aW[k + 0], acc);
      acc = fmaf(hv.y, aW[k + 1], acc);
      acc = fmaf(hv.z, aW[k + 2], acc);
      acc = fmaf(hv.w, aW[k + 3], acc);
    }
    sred[0] = exp_sig(acc + ab[0]);
  }
  if (tid >= NHARM && tid < 128) se[tid] = 0.f;
  __syncthreads();
  if (tid < 64) {
    float s2 = se[tid] + se[tid + 64];
#pragma unroll
    for (int off = 32; off >= 1; off >>= 1) s2 += __shfl_down(s2, off);
    if (tid == 0) sred[1] = s2;
  }
  __syncthreads();
  if (tid < NHARM) {
    out[(size_t)t * NHARM + tid] = sred[0] * se[tid] / (sred[1] + 1e-8f);
  }
}

// ---------------------------------------------------------------------------
extern "C" void kernel_launch(void* const* d_in, const int* in_sizes, int n_in,
                              void* d_out, int out_size, void* d_ws, size_t ws_size,
                              hipStream_t stream)
{
  (void)in_sizes; (void)n_in; (void)out_size;
  const float* f0   = (const float*)d_in[0];
  const float* loud = (const float*)d_in[1];
  const float* Win  = (const float*)d_in[2];
  const float* bin  = (const float*)d_in[3];
  const float* Wi   = (const float*)d_in[4];
  const float* Wh   = (const float*)d_in[5];
  const float* bh   = (const float*)d_in[6];
  const float* h0   = (const float*)d_in[7];
  const float* mlpW = (const float*)d_in[8];
  const float* mlpb = (const float*)d_in[9];
  const float* lnS  = (const float*)d_in[10];
  const float* lnB  = (const float*)d_in[11];
  const float* aW   = (const float*)d_in[12];
  const float* ab   = (const float*)d_in[13];
  const float* hW   = (const float*)d_in[14];
  const float* hb   = (const float*)d_in[15];
  const float* nW   = (const float*)d_in[16];
  const float* nb   = (const float*)d_in[17];
  float* out = (float*)d_out;

  char* ws = (char*)d_ws;
  float*    U     = (float*)(ws);                    // 3072 f32
  float*    V     = (float*)(ws + 12288);            // 3072 f32
  float*    Wc    = (float*)(ws + 24576);            // 3072 f32
  unsigned* slots = (unsigned*)(ws + 36864);         // 2 x 64 x 128B = 16 KB
  u16* bufA = (u16*)(ws + 53248);                               // [T,H] bf16
  u16* bufB = (u16*)(ws + 53248 + (size_t)T_STEPS * H_DIM * 2); // [T,H] bf16

  const size_t needed = 53248 + 2 * (size_t)T_STEPS * H_DIM * 2;  // ~134.3 MB
  if (ws_size < needed) return;  // absmax==max|ref| signals ws too small

  ddsp_precompute<<<16, 256, 0, stream>>>(Win, bin, Wi, h0, U, V, Wc, slots);
  ddsp_gru<<<GRU_NB, 256, 0, stream>>>(f0, loud, Wh, bh, U, V, Wc, h0, slots, bufA);

  dim3 gg(T_STEPS / 64, H_DIM / 64);
  ddsp_gemm_bias<<<gg, 256, 0, stream>>>(bufA, mlpW, mlpb, bufB);
  ddsp_ln_relu<<<T_STEPS, 256, 0, stream>>>(bufB, lnS, lnB);
  ddsp_gemm_bias<<<gg, 256, 0, stream>>>(bufB, mlpW + (size_t)H_DIM * H_DIM, mlpb + H_DIM, bufA);
  ddsp_ln_relu<<<T_STEPS, 256, 0, stream>>>(bufA, lnS + H_DIM, lnB + H_DIM);
  ddsp_gemm_bias<<<gg, 256, 0, stream>>>(bufA, mlpW + 2 * (size_t)H_DIM * H_DIM, mlpb + 2 * H_DIM, bufB);
  ddsp_ln_relu<<<T_STEPS, 256, 0, stream>>>(bufB, lnS + 2 * H_DIM, lnB + 2 * H_DIM);

  ddsp_heads<<<T_STEPS, 256, 0, stream>>>(bufB, aW, ab, hW, hb, nW, nb, out);
}

// Round 12
// 128260.657 us; speedup vs baseline: 1.1530x; 1.1530x over previous
//
#include <hip/hip_runtime.h>
#include <cstdint>
#include <cmath>

// ---------------------------------------------------------------------------
// DDSP decoder on MI355X — inputs/outputs float32 (per reference dtypes).
//   1) precompute: gi_t = f0_t*U + loud_t*V + W  (input GEMM is rank-2+const)
//   2) persistent GRU: 128 blocks x 256 thr (r10 base; r11's 64-block bf16
//      variant doubled per-block compute and regressed). Wh slice (8 cols x
//      3 gates, f32) in LDS (96 KB). Fused h-exchange+barrier, r12 chain:
//      each column group's lane-0 computes gates and DIRECTLY publishes its
//      own [tag,h] dwordx2 pair into the block's 64B slot (8 pairs/line) —
//      no LDS gather, no second barrier. lds_h double-buffered by parity ->
//      ONE __syncthreads per step. Tag==step validates each 8B pair
//      (single-store atomicity); parity double-buffered slot sets are
//      overwrite-safe by the barrier-ordering induction (r8). Poll loop
//      throttled with s_sleep after 2 failed sweeps (r10 showed ~12
//      sweeps/step = IC queue pressure delaying publish visibility).
//      History: r5 fences=L2 wb storm; r6 all-poll-2-lines contention;
//      r7 3-hop master broadcast; r9/r10 sc0 vs sc1 identical (IC is the
//      coherence point either way).
//   3) 3x (64x64-tile GEMM bf16-in/f32-acc/bf16-out + bias) + LN+ReLU.
//   4) heads: per-t block; amp/harm/noise projections, exp_sigmoid, normalize.
// ---------------------------------------------------------------------------

#define T_STEPS 32768
#define H_DIM   1024
#define H3      3072
#define NHARM   100
#define NNOISE  65
#define GRU_NB  128
#define GRU_CPB 8      // columns (h outputs) per block

typedef unsigned short u16;
typedef unsigned uv4 __attribute__((ext_vector_type(4)));
typedef unsigned uv2 __attribute__((ext_vector_type(2)));

__device__ __forceinline__ float b2f(u16 u) {
  union { unsigned u; float f; } x; x.u = ((unsigned)u) << 16; return x.f;
}
__device__ __forceinline__ u16 f2b(float f) {
  unsigned v = __float_as_uint(f);
  unsigned r = (v + 0x7FFFu + ((v >> 16) & 1u)) >> 16;  // RNE
  return (u16)r;
}
__device__ __forceinline__ float sigm(float x) { return 1.0f / (1.0f + expf(-x)); }
__device__ __forceinline__ float exp_sig(float x) {
  float s = sigm(x);
  return 2.0f * expf(2.302585093f * logf(s)) + 1e-7f;  // 2*sigm^ln10 + 1e-7
}

// 64B line read: 4 dwordx4 back-to-back, one drain (sc1 = cache-bypass,
// coherent at the memory-side Infinity Cache). Tags at .x/.z, data at .y/.w.
__device__ __forceinline__ void bypass_load_4x4(const unsigned* p,
    uv4& a, uv4& b, uv4& c, uv4& d) {
  asm volatile("global_load_dwordx4 %0, %4, off sc1\n\t"
               "global_load_dwordx4 %1, %4, off offset:16 sc1\n\t"
               "global_load_dwordx4 %2, %4, off offset:32 sc1\n\t"
               "global_load_dwordx4 %3, %4, off offset:48 sc1\n\t"
               "s_waitcnt vmcnt(0)"
               : "=v"(a), "=v"(b), "=v"(c), "=v"(d) : "v"(p) : "memory");
}
__device__ __forceinline__ void bypass_store_x2(unsigned* p, uv2 v) {
  asm volatile("global_store_dwordx2 %0, %1, off sc1"
               :: "v"(p), "v"(v) : "memory");
}

// slots: 2 parity sets x 128 blocks x 16 u32 (64B line).
// line = 8 pairs [tag, h_bits], pair g at u32 offset 2g (8B-aligned store).

// ---------------------------------------------------------------------------
__global__ __launch_bounds__(256) void ddsp_precompute(
    const float* __restrict__ Win, const float* __restrict__ bin,
    const float* __restrict__ Wi, const float* __restrict__ h0,
    float* __restrict__ U, float* __restrict__ V, float* __restrict__ Wc,
    unsigned* __restrict__ slots)
{
  const int gid = blockIdx.x * 256 + threadIdx.x;
  if (blockIdx.x < 12) {
    const int j = gid;  // 0..3071
    float su = 0.f, sv = 0.f, sw = 0.f;
    for (int h = 0; h < H_DIM; ++h) {
      const float wv = Wi[h * H3 + j];
      su = fmaf(Win[h], wv, su);
      sv = fmaf(Win[H_DIM + h], wv, sv);
      sw = fmaf(bin[h], wv, sw);
    }
    U[j] = su; V[j] = sv; Wc[j] = sw;
  } else {
    const int idx = gid - 12 * 256;           // 0..1023
    if (idx < GRU_NB) {
      unsigned* l0 = slots + idx * 16;              // parity-0: tag 0 + h0
      unsigned* l1 = slots + GRU_NB * 16 + idx * 16;  // parity-1: tag 0 (!=1)
#pragma unroll
      for (int g = 0; g < 8; ++g) {
        l0[2 * g] = 0u;
        l0[2 * g + 1] = __float_as_uint(h0[idx * 8 + g]);
        l1[2 * g] = 0u;
      }
    }
  }
}

// ---------------------------------------------------------------------------
// persistent GRU. 128 blocks x 256 thr. thread = (jl = tid>>5 col 0..7,
// i = tid&31 k-chunk of 32). Wh slice [3][8][1024] f32 staged in LDS once.
// Per step: tid<128 poll one 64B line each (4 dwordx4, throttled spin) ->
// lds_h[par]; ONE barrier; 24 ds_read_b128 + 96 FMA; 32-lane butterfly
// reduce (full sum lands in every lane); lane i==0 of each column does gate
// math and immediately publishes its [tag,h] pair + hall history store.
// ---------------------------------------------------------------------------
__global__ __launch_bounds__(256, 1) void ddsp_gru(
    const float* __restrict__ f0, const float* __restrict__ loud,
    const float* __restrict__ Wh, const float* __restrict__ bh,
    const float* __restrict__ U, const float* __restrict__ V,
    const float* __restrict__ Wc,
    unsigned* __restrict__ slots, u16* __restrict__ hall)
{
  __shared__ float wlds[3 * GRU_CPB * H_DIM];  // 96 KB: [g][c][k]
  __shared__ float lds_h[2][H_DIM];            // 8 KB, parity double-buffer
  const int tid = threadIdx.x;
  const int i  = tid & 31;
  const int jl = tid >> 5;
  const int jg = blockIdx.x * GRU_CPB + jl;

  // One-time LDS weight stage: wlds[g][c][k] = Wh[k][g*1024 + block*8 + c].
  for (int g = 0; g < 3; ++g) {
    for (int c = 0; c < GRU_CPB; ++c) {
      const int col = g * H_DIM + blockIdx.x * GRU_CPB + c;
#pragma unroll
      for (int e = 0; e < 4; ++e) {
        const int k = tid * 4 + e;
        wlds[(g * GRU_CPB + c) * H_DIM + k] = Wh[(size_t)k * H3 + col];
      }
    }
  }

  float ur = 0.f, uz = 0.f, un = 0.f, vr = 0.f, vz = 0.f, vn = 0.f;
  float wr = 0.f, wz = 0.f, wn = 0.f, bhr = 0.f, bhz = 0.f, bhn = 0.f;
  if (i == 0) {
    ur = U[jg]; uz = U[jg + 1024]; un = U[jg + 2048];
    vr = V[jg]; vz = V[jg + 1024]; vn = V[jg + 2048];
    wr = Wc[jg]; wz = Wc[jg + 1024]; wn = Wc[jg + 2048];
    bhr = bh[jg]; bhz = bh[jg + 1024]; bhn = bh[jg + 2048];
  }
  __syncthreads();

  const float* wl0 = wlds + (0 * GRU_CPB + jl) * H_DIM;
  const float* wl1 = wlds + (1 * GRU_CPB + jl) * H_DIM;
  const float* wl2 = wlds + (2 * GRU_CPB + jl) * H_DIM;

  for (int t = 0; t < T_STEPS; ++t) {
    const unsigned tag = (unsigned)t;
    unsigned* slot_rd = slots + (size_t)(t & 1) * GRU_NB * 16;
    unsigned* slot_wr = slots + (size_t)((t + 1) & 1) * GRU_NB * 16;
    float* lh = lds_h[t & 1];

    const float fv = f0[t];
    const float lv = loud[t];

    // poll+assemble: thread tid owns line tid (8 pairs). Throttled spin.
    if (tid < GRU_NB) {
      const unsigned* line = slot_rd + tid * 16;
      uv4 a, b, c, d;
      int spin = 0;
      for (;;) {
        bypass_load_4x4(line, a, b, c, d);
        if (a.x == tag && a.z == tag && b.x == tag && b.z == tag &&
            c.x == tag && c.z == tag && d.x == tag && d.z == tag) break;
        if (++spin >= 2) __builtin_amdgcn_s_sleep(2);  // throttle IC queue
      }
      float4 hA, hB;
      hA.x = __uint_as_float(a.y); hA.y = __uint_as_float(a.w);
      hA.z = __uint_as_float(b.y); hA.w = __uint_as_float(b.w);
      hB.x = __uint_as_float(c.y); hB.y = __uint_as_float(c.w);
      hB.z = __uint_as_float(d.y); hB.w = __uint_as_float(d.w);
      *(float4*)(lh + tid * 8) = hA;
      *(float4*)(lh + tid * 8 + 4) = hB;
    }
    __syncthreads();  // the ONLY barrier per step (lds_h parity-buffered)

    float a0 = 0.f, a1 = 0.f, a2 = 0.f;
    const int kbase = i << 5;  // i*32
#pragma unroll
    for (int it = 0; it < 8; ++it) {
      const int kk = kbase + (((it + i) & 7) << 2);  // rotation spreads banks
      const float4 h4 = *(const float4*)(lh + kk);
      const float4 wa = *(const float4*)(wl0 + kk);
      const float4 wb = *(const float4*)(wl1 + kk);
      const float4 wc4 = *(const float4*)(wl2 + kk);
      a0 = fmaf(wa.x, h4.x, a0); a0 = fmaf(wa.y, h4.y, a0);
      a0 = fmaf(wa.z, h4.z, a0); a0 = fmaf(wa.w, h4.w, a0);
      a1 = fmaf(wb.x, h4.x, a1); a1 = fmaf(wb.y, h4.y, a1);
      a1 = fmaf(wb.z, h4.z, a1); a1 = fmaf(wb.w, h4.w, a1);
      a2 = fmaf(wc4.x, h4.x, a2); a2 = fmaf(wc4.y, h4.y, a2);
      a2 = fmaf(wc4.z, h4.z, a2); a2 = fmaf(wc4.w, h4.w, a2);
    }
    // butterfly reduce: full sum ends up in EVERY lane of the 32-lane group
#pragma unroll
    for (int m = 1; m < 32; m <<= 1) {
      a0 += __shfl_xor(a0, m);
      a1 += __shfl_xor(a1, m);
      a2 += __shfl_xor(a2, m);
    }
    // per-column gate math + DIRECT publish (no gather, no second barrier)
    if (i == 0) {
      const float gir = fmaf(fv, ur, fmaf(lv, vr, wr));
      const float giz = fmaf(fv, uz, fmaf(lv, vz, wz));
      const float gin = fmaf(fv, un, fmaf(lv, vn, wn));
      const float r = sigm(gir + a0 + bhr);
      const float z = sigm(giz + a1 + bhz);
      const float n = tanhf(fmaf(r, a2 + bhn, gin));  // b_h[n] inside r*( )
      const float hp = lh[jg];
      const float hn = (1.0f - z) * n + z * hp;
      uv2 pq;
      pq.x = (unsigned)(t + 1);
      pq.y = __float_as_uint(hn);
      bypass_store_x2(slot_wr + blockIdx.x * 16 + jl * 2, pq);
      hall[(size_t)t * H_DIM + jg] = f2b(hn);  // cached store, off the path
    }
  }
}

// ---------------------------------------------------------------------------
// GEMM: Y[T,1024](bf16) = X[T,1024](bf16) @ W[1024,1024](f32) + bias(f32)
// ---------------------------------------------------------------------------
__global__ __launch_bounds__(256) void ddsp_gemm_bias(
    const u16* __restrict__ X, const float* __restrict__ Wt,
    const float* __restrict__ bias, u16* __restrict__ Y)
{
  __shared__ float As[16][64];
  __shared__ float Bs[16][64];
  const int tid = threadIdx.x;
  const int R0 = blockIdx.x * 64;
  const int N0 = blockIdx.y * 64;
  const int tx = tid & 15, ty = tid >> 4;
  const int am = tid >> 2, ak = (tid & 3) * 4;
  const int bk = tid >> 4, bn = (tid & 15) * 4;
  float acc[4][4] = {};

  for (int k0 = 0; k0 < H_DIM; k0 += 16) {
    const ushort4 a4 = *(const ushort4*)(X + (size_t)(R0 + am) * H_DIM + k0 + ak);
    const float4 b4 = *(const float4*)(Wt + (size_t)(k0 + bk) * H_DIM + N0 + bn);
    As[ak + 0][am] = b2f(a4.x); As[ak + 1][am] = b2f(a4.y);
    As[ak + 2][am] = b2f(a4.z); As[ak + 3][am] = b2f(a4.w);
    *(float4*)&Bs[bk][bn] = b4;
    __syncthreads();
#pragma unroll
    for (int kk = 0; kk < 16; ++kk) {
      const float4 av = *(const float4*)&As[kk][ty * 4];
      const float4 bv = *(const float4*)&Bs[kk][tx * 4];
      const float a[4] = {av.x, av.y, av.z, av.w};
      const float b[4] = {bv.x, bv.y, bv.z, bv.w};
#pragma unroll
      for (int mi = 0; mi < 4; ++mi)
#pragma unroll
        for (int ni = 0; ni < 4; ++ni)
          acc[mi][ni] = fmaf(a[mi], b[ni], acc[mi][ni]);
    }
    __syncthreads();
  }
  const float4 bv4 = *(const float4*)(bias + N0 + tx * 4);
#pragma unroll
  for (int mi = 0; mi < 4; ++mi) {
    ushort4 st;
    st.x = f2b(acc[mi][0] + bv4.x);
    st.y = f2b(acc[mi][1] + bv4.y);
    st.z = f2b(acc[mi][2] + bv4.z);
    st.w = f2b(acc[mi][3] + bv4.w);
    *(ushort4*)(Y + (size_t)(R0 + ty * 4 + mi) * H_DIM + N0 + tx * 4) = st;
  }
}

// ---------------------------------------------------------------------------
__global__ __launch_bounds__(256) void ddsp_ln_relu(
    u16* __restrict__ Y, const float* __restrict__ scale, const float* __restrict__ bias)
{
  __shared__ float wsum[4], wsq[4];
  const int row = blockIdx.x, tid = threadIdx.x;
  const ushort4 r4 = *(const ushort4*)(Y + (size_t)row * H_DIM + tid * 4);
  float x[4] = {b2f(r4.x), b2f(r4.y), b2f(r4.z), b2f(r4.w)};
  float s = x[0] + x[1] + x[2] + x[3];
  float q = x[0] * x[0] + x[1] * x[1] + x[2] * x[2] + x[3] * x[3];
#pragma unroll
  for (int off = 32; off >= 1; off >>= 1) {
    s += __shfl_down(s, off);
    q += __shfl_down(q, off);
  }
  if ((tid & 63) == 0) { wsum[tid >> 6] = s; wsq[tid >> 6] = q; }
  __syncthreads();
  const float ts = wsum[0] + wsum[1] + wsum[2] + wsum[3];
  const float tq = wsq[0] + wsq[1] + wsq[2] + wsq[3];
  const float mu = ts * (1.0f / H_DIM);
  const float var = tq * (1.0f / H_DIM) - mu * mu;
  const float rstd = rsqrtf(fmaxf(var, 0.f) + 1e-6f);
  const float4 sc = *(const float4*)(scale + tid * 4);
  const float4 bi = *(const float4*)(bias + tid * 4);
  ushort4 st;
  st.x = f2b(fmaxf((x[0] - mu) * rstd * sc.x + bi.x, 0.f));
  st.y = f2b(fmaxf((x[1] - mu) * rstd * sc.y + bi.y, 0.f));
  st.z = f2b(fmaxf((x[2] - mu) * rstd * sc.z + bi.z, 0.f));
  st.w = f2b(fmaxf((x[3] - mu) * rstd * sc.w + bi.w, 0.f));
  *(ushort4*)(Y + (size_t)row * H_DIM + tid * 4) = st;
}

// ---------------------------------------------------------------------------
__global__ __launch_bounds__(256) void ddsp_heads(
    const u16* __restrict__ Hf,
    const float* __restrict__ aW, const float* __restrict__ ab,
    const float* __restrict__ hW, const float* __restrict__ hb,
    const float* __restrict__ nW, const float* __restrict__ nb,
    float* __restrict__ out)
{
  __shared__ float lh[H_DIM];
  __shared__ float se[128];
  __shared__ float sred[2];
  const int t = blockIdx.x, tid = threadIdx.x;
  const ushort4 h4 = *(const ushort4*)(Hf + (size_t)t * H_DIM + tid * 4);
  lh[tid * 4 + 0] = b2f(h4.x); lh[tid * 4 + 1] = b2f(h4.y);
  lh[tid * 4 + 2] = b2f(h4.z); lh[tid * 4 + 3] = b2f(h4.w);
  __syncthreads();

  if (tid < NHARM) {
    float acc = 0.f;
    for (int k = 0; k < H_DIM; k += 4) {
      const float4 hv = *(const float4*)(lh + k);
      acc = fmaf(hv.x, hW[(k + 0) * NHARM + tid], acc);
      acc = fmaf(hv.y, hW[(k + 1) * NHARM + tid], acc);
      acc = fmaf(hv.z, hW[(k + 2) * NHARM + tid], acc);
      acc = fmaf(hv.w, hW[(k + 3) * NHARM + tid], acc);
    }
    se[tid] = exp_sig(acc + hb[tid]);
  } else if (tid < NHARM + NNOISE) {
    const int n = tid - NHARM;
    float acc = 0.f;
    for (int k = 0; k < H_DIM; k += 4) {
      const float4 hv = *(const float4*)(lh + k);
      acc = fmaf(hv.x, nW[(k + 0) * NNOISE + n], acc);
      acc = fmaf(hv.y, nW[(k + 1) * NNOISE + n], acc);
      acc = fmaf(hv.z, nW[(k + 2) * NNOISE + n], acc);
      acc = fmaf(hv.w, nW[(k + 3) * NNOISE + n], acc);
    }
    out[(size_t)T_STEPS * NHARM + (size_t)t * NNOISE + n] = acc + nb[n];
  } else if (tid == NHARM + NNOISE) {
    float acc = 0.f;
    for (int k = 0; k < H_DIM; k += 4) {
      const float4 hv = *(const float4*)(lh + k);
      acc = fmaf(hv.x, aW[k + 0], acc);
      acc = fmaf(hv.y, aW[k + 1], acc);
      acc = fmaf(hv.z, aW[k + 2], acc);
      acc = fmaf(hv.w, aW[k + 3], acc);
    }
    sred[0] = exp_sig(acc + ab[0]);
  }
  if (tid >= NHARM && tid < 128) se[tid] = 0.f;
  __syncthreads();
  if (tid < 64) {
    float s2 = se[tid] + se[tid + 64];
#pragma unroll
    for (int off = 32; off >= 1; off >>= 1) s2 += __shfl_down(s2, off);
    if (tid == 0) sred[1] = s2;
  }
  __syncthreads();
  if (tid < NHARM) {
    out[(size_t)t * NHARM + tid] = sred[0] * se[tid] / (sred[1] + 1e-8f);
  }
}

// ---------------------------------------------------------------------------
extern "C" void kernel_launch(void* const* d_in, const int* in_sizes, int n_in,
                              void* d_out, int out_size, void* d_ws, size_t ws_size,
                              hipStream_t stream)
{
  (void)in_sizes; (void)n_in; (void)out_size;
  const float* f0   = (const float*)d_in[0];
  const float* loud = (const float*)d_in[1];
  const float* Win  = (const float*)d_in[2];
  const float* bin  = (const float*)d_in[3];
  const float* Wi   = (const float*)d_in[4];
  const float* Wh   = (const float*)d_in[5];
  const float* bh   = (const float*)d_in[6];
  const float* h0   = (const float*)d_in[7];
  const float* mlpW = (const float*)d_in[8];
  const float* mlpb = (const float*)d_in[9];
  const float* lnS  = (const float*)d_in[10];
  const float* lnB  = (const float*)d_in[11];
  const float* aW   = (const float*)d_in[12];
  const float* ab   = (const float*)d_in[13];
  const float* hW   = (const float*)d_in[14];
  const float* hb   = (const float*)d_in[15];
  const float* nW   = (const float*)d_in[16];
  const float* nb   = (const float*)d_in[17];
  float* out = (float*)d_out;

  char* ws = (char*)d_ws;
  float*    U     = (float*)(ws);                    // 3072 f32
  float*    V     = (float*)(ws + 12288);            // 3072 f32
  float*    Wc    = (float*)(ws + 24576);            // 3072 f32
  unsigned* slots = (unsigned*)(ws + 36864);         // 2 x 128 x 64B = 16 KB
  u16* bufA = (u16*)(ws + 53248);                               // [T,H] bf16
  u16* bufB = (u16*)(ws + 53248 + (size_t)T_STEPS * H_DIM * 2); // [T,H] bf16

  const size_t needed = 53248 + 2 * (size_t)T_STEPS * H_DIM * 2;  // ~134.3 MB
  if (ws_size < needed) return;  // absmax==max|ref| signals ws too small

  ddsp_precompute<<<16, 256, 0, stream>>>(Win, bin, Wi, h0, U, V, Wc, slots);
  ddsp_gru<<<GRU_NB, 256, 0, stream>>>(f0, loud, Wh, bh, U, V, Wc, slots, bufA);

  dim3 gg(T_STEPS / 64, H_DIM / 64);
  ddsp_gemm_bias<<<gg, 256, 0, stream>>>(bufA, mlpW, mlpb, bufB);
  ddsp_ln_relu<<<T_STEPS, 256, 0, stream>>>(bufB, lnS, lnB);
  ddsp_gemm_bias<<<gg, 256, 0, stream>>>(bufB, mlpW + (size_t)H_DIM * H_DIM, mlpb + H_DIM, bufA);
  ddsp_ln_relu<<<T_STEPS, 256, 0, stream>>>(bufA, lnS + H_DIM, lnB + H_DIM);
  ddsp_gemm_bias<<<gg, 256, 0, stream>>>(bufA, mlpW + 2 * (size_t)H_DIM * H_DIM, mlpb + 2 * H_DIM, bufB);
  ddsp_ln_relu<<<T_STEPS, 256, 0, stream>>>(bufB, lnS + 2 * H_DIM, lnB + 2 * H_DIM);

  ddsp_heads<<<T_STEPS, 256, 0, stream>>>(bufB, aW, ab, hW, hb, nW, nb, out);
}